// Round 1
// baseline (301.923 us; speedup 1.0000x reference)
//
#include <hip/hip_runtime.h>
#include <stdint.h>

typedef unsigned short ushort_t;
typedef __attribute__((__ext_vector_type__(8))) __bf16 bf16x8;
typedef __attribute__((__ext_vector_type__(4))) float f32x4;

// ---- f32 -> bf16 RNE (bit trick; inputs finite) ----
__device__ inline ushort_t f2bf(float f) {
    unsigned int u = __float_as_uint(f);
    u = u + 0x7FFFu + ((u >> 16) & 1u);
    return (ushort_t)(u >> 16);
}

#define GLOAD16(gp, lp) __builtin_amdgcn_global_load_lds( \
    (__attribute__((address_space(1))) void*)(gp),        \
    (__attribute__((address_space(3))) void*)(lp), 16, 0, 0)

// =====================================================================
// Generic NT GEMM: C[M,N] = A[M,K] * B[N,K]^T   (A,B bf16-as-ushort)
// 128x128 tile, BK=32, 256 threads = 4 waves (2x2 of 64x64), MFMA 16x16x32.
// MODE 0: C bf16, optional bias (f32), scale
// MODE 1: C bf16 transposed per-batch (Vt[b][col][row&2047]) + bias
// MODE 2: C f32, scale (scores)
// MODE 3: C f32 + bias (final output)
// Grid: (N/128, M/128, Z). A,B,C advanced by z*sA / z*sB / z*sC (elements).
// =====================================================================
template<int MODE>
__global__ __launch_bounds__(256)
void gemm_nt(const ushort_t* __restrict__ A, const ushort_t* __restrict__ B,
             void* __restrict__ Cv, const float* __restrict__ bias,
             int K, int lda, int ldb, int ldc, float scale,
             long long sA, long long sB, long long sC)
{
    __shared__ __align__(16) char lds[16384];
    char* ldsA = lds;
    char* ldsB = lds + 8192;

    const int t = threadIdx.x;
    const int z = blockIdx.z;
    A += (size_t)z * (size_t)sA;
    B += (size_t)z * (size_t)sB;

    const int rowBase = blockIdx.y * 128;
    const int colBase = blockIdx.x * 128;

    const int w    = t >> 6;
    const int lane = t & 63;
    const int wr = w >> 1, wc = w & 1;
    const int lr = lane & 15, lg = lane >> 4;

    f32x4 acc[4][4];
#pragma unroll
    for (int i = 0; i < 4; ++i)
#pragma unroll
        for (int j = 0; j < 4; ++j)
            acc[i][j] = (f32x4){0.f, 0.f, 0.f, 0.f};

    for (int kt = 0; kt < K; kt += 32) {
        // stage A,B tiles (128x32 bf16 each) via global_load_lds width=16
#pragma unroll
        for (int i = 0; i < 2; ++i) {
            const int L   = i * 256 + t;       // 16B granule index, 0..511
            const int row = L >> 2;            // 0..127
            const int g   = L & 3;             // granule within row (8 elems)
            const ushort_t* ga = A + (size_t)(rowBase + row) * (size_t)lda + (kt + g * 8);
            GLOAD16(ga, ldsA + L * 16);
            const ushort_t* gb = B + (size_t)(colBase + row) * (size_t)ldb + (kt + g * 8);
            GLOAD16(gb, ldsB + L * 16);
        }
        __syncthreads();

        const bf16x8* A8 = (const bf16x8*)ldsA;
        const bf16x8* B8 = (const bf16x8*)ldsB;
        bf16x8 af[4], bq[4];
#pragma unroll
        for (int mi = 0; mi < 4; ++mi)
            af[mi] = A8[(wr * 64 + mi * 16 + lr) * 4 + lg];
#pragma unroll
        for (int ni = 0; ni < 4; ++ni)
            bq[ni] = B8[(wc * 64 + ni * 16 + lr) * 4 + lg];
#pragma unroll
        for (int mi = 0; mi < 4; ++mi)
#pragma unroll
            for (int ni = 0; ni < 4; ++ni)
                acc[mi][ni] = __builtin_amdgcn_mfma_f32_16x16x32_bf16(
                    af[mi], bq[ni], acc[mi][ni], 0, 0, 0);
        __syncthreads();
    }

    // ---- epilogue ----
#pragma unroll
    for (int mi = 0; mi < 4; ++mi) {
#pragma unroll
        for (int ni = 0; ni < 4; ++ni) {
#pragma unroll
            for (int r = 0; r < 4; ++r) {
                const int grow = rowBase + wr * 64 + mi * 16 + lg * 4 + r;
                const int gcol = colBase + wc * 64 + ni * 16 + lr;
                float v = acc[mi][ni][r] * scale;
                if (MODE == 0) {
                    if (bias) v += bias[gcol];
                    ushort_t* C = (ushort_t*)Cv + (size_t)z * (size_t)sC;
                    C[(size_t)grow * (size_t)ldc + gcol] = f2bf(v);
                } else if (MODE == 1) {
                    v += bias[gcol];
                    ushort_t* C = (ushort_t*)Cv;
                    const int b = grow >> 11, n = grow & 2047;
                    C[(size_t)b * (512 * 2048) + (size_t)gcol * 2048 + n] = f2bf(v);
                } else if (MODE == 2) {
                    float* C = (float*)Cv + (size_t)z * (size_t)sC;
                    C[(size_t)grow * (size_t)ldc + gcol] = v;
                } else {
                    float* C = (float*)Cv;
                    C[(size_t)grow * (size_t)ldc + gcol] = v + bias[gcol];
                }
            }
        }
    }
}

// =====================================================================
// f32 -> bf16 convert, 4 elems/thread
// =====================================================================
__global__ __launch_bounds__(256)
void cvt_bf16(const float* __restrict__ src, ushort_t* __restrict__ dst, int n4)
{
    int i = blockIdx.x * 256 + threadIdx.x;
    if (i >= n4) return;
    float4 v = ((const float4*)src)[i];
    union { ushort_t h[4]; uint2 u; } p;
    p.h[0] = f2bf(v.x); p.h[1] = f2bf(v.y); p.h[2] = f2bf(v.z); p.h[3] = f2bf(v.w);
    ((uint2*)dst)[i] = p.u;
}

// =====================================================================
// Row softmax + intensity add, writes bf16 attn in-place into first half
// of each f32 S row. One block (256 thr) per row of 2048.
// =====================================================================
__global__ __launch_bounds__(256)
void softmax_add(float* __restrict__ Sf, const float* __restrict__ inten)
{
    const int R = blockIdx.x;          // 0..16383 (= b*2048 + r)
    const int t = threadIdx.x;
    const int w = t >> 6, lane = t & 63;
    float* srow = Sf + (size_t)R * 2048;
    const float* irow = inten + (size_t)R * 2048;   // [B][N][N] flat == R*2048

    float x[8];
    {
        float4 v0 = *(const float4*)(srow + t * 8);
        float4 v1 = *(const float4*)(srow + t * 8 + 4);
        x[0] = v0.x; x[1] = v0.y; x[2] = v0.z; x[3] = v0.w;
        x[4] = v1.x; x[5] = v1.y; x[6] = v1.z; x[7] = v1.w;
    }

    float m = x[0];
#pragma unroll
    for (int j = 1; j < 8; ++j) m = fmaxf(m, x[j]);
#pragma unroll
    for (int off = 32; off > 0; off >>= 1) m = fmaxf(m, __shfl_xor(m, off));

    __shared__ float red[8];
    if (lane == 0) red[w] = m;
    __syncthreads();          // also guarantees all S reads are done
    m = fmaxf(fmaxf(red[0], red[1]), fmaxf(red[2], red[3]));

    float e[8], s = 0.f;
#pragma unroll
    for (int j = 0; j < 8; ++j) { e[j] = __expf(x[j] - m); s += e[j]; }
#pragma unroll
    for (int off = 32; off > 0; off >>= 1) s += __shfl_xor(s, off);
    if (lane == 0) red[4 + w] = s;
    __syncthreads();
    s = red[4] + red[5] + red[6] + red[7];
    const float inv = 1.f / s;

    float4 i0 = *(const float4*)(irow + t * 8);
    float4 i1 = *(const float4*)(irow + t * 8 + 4);
    float o[8] = { e[0]*inv + i0.x, e[1]*inv + i0.y, e[2]*inv + i0.z, e[3]*inv + i0.w,
                   e[4]*inv + i1.x, e[5]*inv + i1.y, e[6]*inv + i1.z, e[7]*inv + i1.w };

    union { ushort_t h[8]; uint4 u; } p;
#pragma unroll
    for (int j = 0; j < 8; ++j) p.h[j] = f2bf(o[j]);
    ushort_t* arow = (ushort_t*)Sf + (size_t)R * 4096;   // bf16 row over f32 row
    *(uint4*)(arow + t * 8) = p.u;
}

// =====================================================================
extern "C" void kernel_launch(void* const* d_in, const int* in_sizes, int n_in,
                              void* d_out, int out_size, void* d_ws, size_t ws_size,
                              hipStream_t stream)
{
    const float* X    = (const float*)d_in[0];
    const float* inten= (const float*)d_in[1];
    const float* WQw  = (const float*)d_in[2];
    const float* WQb  = (const float*)d_in[3];
    const float* WKw  = (const float*)d_in[4];
    const float* WKb  = (const float*)d_in[5];
    const float* WVw  = (const float*)d_in[6];
    const float* WVb  = (const float*)d_in[7];
    const float* Wow  = (const float*)d_in[8];
    const float* Wob  = (const float*)d_in[9];
    float* out = (float*)d_out;

    char* ws = (char*)d_ws;
    // workspace layout (bytes)
    ushort_t* Xb   = (ushort_t*)(ws + 0);              // 16384x512       16 MiB
    ushort_t* Wqb  = (ushort_t*)(ws + 16777216);       // 512x512        0.5 MiB
    ushort_t* Wkb  = (ushort_t*)(ws + 17301504);
    ushort_t* Wvb  = (ushort_t*)(ws + 17825792);
    ushort_t* Wob2 = (ushort_t*)(ws + 18350080);
    ushort_t* Qb   = (ushort_t*)(ws + 18874368);       // 8x2048x512      16 MiB
    ushort_t* Kb   = (ushort_t*)(ws + 35651584);
    ushort_t* Vt   = (ushort_t*)(ws + 52428800);       // 8x512x2048      16 MiB
    ushort_t* out1 = (ushort_t*)(ws + 69206016);       // 16384x512       16 MiB
    float*    Sf   = (float*)   (ws + 85983232);       // 8x2048x2048    128 MiB

    const float scale = 0.044194173824159216f;         // 1/sqrt(512)

    // converts
    cvt_bf16<<<dim3(8192), dim3(256), 0, stream>>>(X,   Xb,   2097152);
    cvt_bf16<<<dim3(256),  dim3(256), 0, stream>>>(WQw, Wqb,  65536);
    cvt_bf16<<<dim3(256),  dim3(256), 0, stream>>>(WKw, Wkb,  65536);
    cvt_bf16<<<dim3(256),  dim3(256), 0, stream>>>(WVw, Wvb,  65536);
    cvt_bf16<<<dim3(256),  dim3(256), 0, stream>>>(Wow, Wob2, 65536);

    // Q = Xb @ WQ^T + bq          [16384,512]
    gemm_nt<0><<<dim3(4, 128, 1), dim3(256), 0, stream>>>(
        Xb, Wqb, Qb, WQb, 512, 512, 512, 512, 1.f, 0, 0, 0);
    // K = Xb @ WK^T + bk
    gemm_nt<0><<<dim3(4, 128, 1), dim3(256), 0, stream>>>(
        Xb, Wkb, Kb, WKb, 512, 512, 512, 512, 1.f, 0, 0, 0);
    // Vt[b][d][n] = (Xb @ WV^T + bv)^T
    gemm_nt<1><<<dim3(4, 128, 1), dim3(256), 0, stream>>>(
        Xb, Wvb, Vt, WVb, 512, 512, 512, 0, 1.f, 0, 0, 0);

    // S = scale * Q @ K^T   per batch   [2048,2048] f32
    gemm_nt<2><<<dim3(16, 16, 8), dim3(256), 0, stream>>>(
        Qb, Kb, Sf, nullptr, 512, 512, 512, 2048, scale,
        2048LL * 512, 2048LL * 512, 2048LL * 2048);

    // softmax rows + intensity, write bf16 attn into S rows (lda becomes 4096)
    softmax_add<<<dim3(16384), dim3(256), 0, stream>>>(Sf, inten);

    // out1 = attn @ Vt^T   per batch   [2048,512] bf16
    gemm_nt<0><<<dim3(4, 16, 8), dim3(256), 0, stream>>>(
        (const ushort_t*)Sf, Vt, out1, nullptr, 2048, 4096, 2048, 512, 1.f,
        2048LL * 4096, 512LL * 2048, 2048LL * 512);

    // out = out1 @ Wo^T + bo     [16384,512] f32
    gemm_nt<3><<<dim3(4, 128, 1), dim3(256), 0, stream>>>(
        out1, Wob2, out, Wob, 512, 512, 512, 512, 1.f, 0, 0, 0);
}